// Round 13
// baseline (257.744 us; speedup 1.0000x reference)
//
#include <hip/hip_runtime.h>
#include <hip/hip_bf16.h>

#define EPS 1e-5f

typedef __bf16 bf16x8 __attribute__((ext_vector_type(8)));
typedef float f32x4 __attribute__((ext_vector_type(4)));
typedef unsigned short ushort_t;

#define GLDS16(gp, lp) __builtin_amdgcn_global_load_lds( \
    (const __attribute__((address_space(1))) unsigned int*)(gp), \
    (__attribute__((address_space(3))) unsigned int*)(lp), 16, 0, 0)

__device__ __forceinline__ unsigned short f2bf(float f) {
    unsigned int u = __float_as_uint(f);
    u += 0x7fffu + ((u >> 16) & 1u);   // RNE
    return (unsigned short)(u >> 16);
}

// ---------------- generic f32 [R][C] -> bf16 [R2][C2] zero-padded convert (device fn) ---------
__device__ __forceinline__ void convert_pad_body(
    const float* __restrict__ src, ushort_t* __restrict__ dst,
    int R, int C, int R2, int C2, long long start, long long stride)
{
    int cpr = C2 >> 2;
    long long nchunks = (long long)R2 * cpr;
    for (long long idx = start; idx < nchunks; idx += stride) {
        int row = (int)(idx / cpr);
        int col = ((int)(idx - (long long)row * cpr)) << 2;
        float4 v = make_float4(0.f, 0.f, 0.f, 0.f);
        if (row < R && col < C)
            v = *reinterpret_cast<const float4*>(src + (size_t)row * C + col);
        union { unsigned short h[4]; uint2 u; } pk;
        pk.h[0] = f2bf(v.x); pk.h[1] = f2bf(v.y);
        pk.h[2] = f2bf(v.z); pk.h[3] = f2bf(v.w);
        *reinterpret_cast<uint2*>(dst + (size_t)row * C2 + col) = pk.u;
    }
}

// ---------------- kernel 1: ALL independent prep work in one dispatch ----------------
// blocks [0,1024): frontend   [1024,4224): fcw convert   [4224,26099): ent convert
__global__ __launch_bounds__(256) void prep_all_kernel(
    const float* __restrict__ fc_w, ushort_t* __restrict__ fcw,
    const int* __restrict__ eid, const int* __restrict__ rid,
    const float* __restrict__ ent_emb, const float* __restrict__ rel_emb,
    const float* __restrict__ filt_w, const float* __restrict__ filt1_w,
    const float* __restrict__ bn0_s, const float* __restrict__ bn0_b,
    const float* __restrict__ bn0_m, const float* __restrict__ bn0_v,
    const float* __restrict__ bn1_s, const float* __restrict__ bn1_b,
    const float* __restrict__ bn1_m, const float* __restrict__ bn1_v,
    ushort_t* __restrict__ act, ushort_t* __restrict__ E_bf)
{
    __shared__ float img[20][20];
    __shared__ float fA[16][9];
    __shared__ float fB[16][9];
    __shared__ float a1[16], b1[16];

    int t = threadIdx.x;
    if (blockIdx.x >= 4224) {
        long long start = (long long)(blockIdx.x - 4224) * 256 + t;
        convert_pad_body(ent_emb, E_bf, 100000, 200, 100000, 224, start, 21875LL * 256);
        return;
    }
    if (blockIdx.x >= 1024) {
        long long start = (long long)(blockIdx.x - 1024) * 256 + t;
        convert_pad_body(fc_w, fcw, 200, 12800, 256, 12800, start, 3200LL * 256);
        return;
    }

    int b = blockIdx.x;
    int e = eid[b], r = rid[b];

    float a0 = bn0_s[0] * rsqrtf(bn0_v[0] + EPS);
    float c0 = bn0_b[0] - bn0_m[0] * a0;

    for (int p = t; p < 400; p += 256) {
        int i = p / 20, j = p - (p / 20) * 20;
        int src;
        if (i < 10) src = (j < 10) ? (i * 40 + j) : ((j - 10) * 40 + 30 + i);
        else        src = (j < 10) ? ((i - 10) * 40 + 20 + j) : ((j - 10) * 40 + 10 + (i - 10));
        float v = (src < 200) ? ent_emb[(size_t)e * 200 + src]
                              : rel_emb[(size_t)r * 200 + (src - 200)];
        img[i][j] = v * a0 + c0;
    }
    for (int p = t; p < 144; p += 256) fA[p / 9][p % 9] = filt_w[(size_t)r * 144 + p];
    for (int p = t; p < 144; p += 256) fB[p / 9][p % 9] = filt1_w[(size_t)r * 144 + p];
    if (t < 16) {
        float a = bn1_s[t] * rsqrtf(bn1_v[t] + EPS);
        a1[t] = a;
        b1[t] = bn1_b[t] - bn1_m[t] * a;
    }
    __syncthreads();

    for (int idx = t; idx < 12800; idx += 256) {
        int c = idx / 400;
        int p = idx - c * 400;
        int i = p / 20, j = p - (p / 20) * 20;
        int ch = c & 15;
        float acc = 0.f;
        if (c < 16) {
            #pragma unroll
            for (int di = 0; di < 3; ++di) {
                int ii = i + di - 1;
                if (ii < 0 || ii >= 20) continue;
                #pragma unroll
                for (int dj = 0; dj < 3; ++dj) {
                    int jj = j + dj - 1;
                    if (jj >= 0 && jj < 20) acc += img[ii][jj] * fA[ch][di * 3 + dj];
                }
            }
        } else {
            #pragma unroll
            for (int dj = 0; dj < 9; ++dj) {
                int jj = j + dj - 4;
                if (jj >= 0 && jj < 20) acc += img[i][jj] * fB[ch][dj];
            }
        }
        float v = fmaxf(acc * a1[ch] + b1[ch], 0.f);
        act[(size_t)b * 12800 + idx] = f2bf(v);
    }
}

// ---------------- kernel 2: fc GEMM only (640 blocks, split-K=20) ----------------
__global__ __launch_bounds__(256) void fc_gemm_kernel(
    const ushort_t* __restrict__ act,   // [1024][12800] bf16
    const ushort_t* __restrict__ fcw,   // [256][12800] bf16 (rows 200.. zero)
    float* __restrict__ part)           // [20][1024][256] f32
{
    __shared__ ushort_t lA[128 * 64];
    __shared__ ushort_t lB[64 * 64];

    int t = threadIdx.x;
    int bx = blockIdx.x;
    int mt = bx & 7;
    int nt = (bx >> 3) & 3;
    int ks = bx >> 5;
    int m0 = mt * 128, n0 = nt * 64, k0 = ks * 640;

    int lane = t & 63, w = t >> 6;
    int wm = (w >> 1) * 64;
    int wn = (w & 1) * 32;

    f32x4 acc[4][2] = {};

    for (int step = 0; step < 10; ++step) {
        int kk = k0 + step * 64;
        for (int c = w; c < 16; c += 4) {
            int elem = c * 512 + lane * 8;
            int row = elem >> 6, col = elem & 63;
            GLDS16(act + (size_t)(m0 + row) * 12800 + kk + col, lA + c * 512);
        }
        for (int c = w; c < 8; c += 4) {
            int elem = c * 512 + lane * 8;
            int row = elem >> 6, col = elem & 63;
            GLDS16(fcw + (size_t)(n0 + row) * 12800 + kk + col, lB + c * 512);
        }
        __syncthreads();
        #pragma unroll
        for (int kq = 0; kq < 2; ++kq) {
            bf16x8 af[4], bfr[2];
            #pragma unroll
            for (int mf = 0; mf < 4; ++mf) {
                int row = wm + mf * 16 + (lane & 15);
                af[mf] = *reinterpret_cast<const bf16x8*>(lA + row * 64 + kq * 32 + (lane >> 4) * 8);
            }
            #pragma unroll
            for (int nf = 0; nf < 2; ++nf) {
                int row = wn + nf * 16 + (lane & 15);
                bfr[nf] = *reinterpret_cast<const bf16x8*>(lB + row * 64 + kq * 32 + (lane >> 4) * 8);
            }
            #pragma unroll
            for (int mf = 0; mf < 4; ++mf)
                #pragma unroll
                for (int nf = 0; nf < 2; ++nf)
                    acc[mf][nf] = __builtin_amdgcn_mfma_f32_16x16x32_bf16(af[mf], bfr[nf], acc[mf][nf], 0, 0, 0);
        }
        __syncthreads();
    }

    float* outp = part + (size_t)ks * 1024 * 256;
    #pragma unroll
    for (int mf = 0; mf < 4; ++mf) {
        #pragma unroll
        for (int nf = 0; nf < 2; ++nf) {
            int colg = n0 + wn + nf * 16 + (lane & 15);
            int rowb = (lane >> 4) * 4;
            #pragma unroll
            for (int j = 0; j < 4; ++j) {
                int rowg = m0 + wm + mf * 16 + rowb + j;
                outp[(size_t)rowg * 256 + colg] = acc[mf][nf][j];
            }
        }
    }
}

// ---------------- reduce partials + fc_b + bn2 + relu -> h bf16 [1024][224] ----------------
__global__ __launch_bounds__(256) void reduce_bn2_kernel(
    const float* __restrict__ part, const float* __restrict__ fc_b,
    const float* __restrict__ bn2_s, const float* __restrict__ bn2_b,
    const float* __restrict__ bn2_m, const float* __restrict__ bn2_v,
    ushort_t* __restrict__ h)
{
    int idx = blockIdx.x * 256 + threadIdx.x;
    if (idx >= 1024 * 224) return;
    int m = idx / 224, n = idx - m * 224;
    float v = 0.f;
    if (n < 200) {
        float s = 0.f;
        #pragma unroll 4
        for (int k = 0; k < 20; ++k) s += part[(size_t)k * 1024 * 256 + (size_t)m * 256 + n];
        s += fc_b[n];
        float a = bn2_s[n] * rsqrtf(bn2_v[n] + EPS);
        v = fmaxf((s - bn2_m[n]) * a + bn2_b[n], 0.f);
    }
    h[idx] = f2bf(v);
}

// ---------------- big GEMM v12: R12 structure, PLAIN stores in transposed epilogue ----------------
// h[1024][224] x E[100000][224]^T + bias -> sigmoid -> out [1024][100000]
// Single-variable A/B vs the R12 champion: nontemporal -> plain stores. With the
// transposed epilogue every burst covers full aligned 128-B lines, so the R4
// write-allocate hazard (partial-line plain stores) no longer applies; plain
// stores get the same L2 write-combining path the 6.8 TB/s fill kernels use.
__global__ __launch_bounds__(256) void big_gemm_kernel(
    const ushort_t* __restrict__ hm,    // [1024][224] bf16
    const ushort_t* __restrict__ em,    // [100000][224] bf16 (cols 200.. zero)
    const float* __restrict__ out_bias, // [100000]
    float* __restrict__ out)            // [1024][100000]
{
    __shared__ ushort_t lA[2][64 * 32];    // 4 KB x2
    __shared__ ushort_t lB[2][128 * 32];   // 8 KB x2
    __shared__ float tr[32][132];          // 16.9 KB, separate — no aliasing

    // bijective XCD swizzle: 12512 = 8 x 1564
    int phys = blockIdx.x;
    int virt = (phys & 7) * 1564 + (phys >> 3);
    int mt = virt & 15;     // 16 M tiles of 64 rows
    int nt = virt >> 4;     // 782 N tiles of 128 cols
    int m0 = mt * 64, n0 = nt * 128;

    int t = threadIdx.x;
    int lane = t & 63, w = t >> 6;
    int wm = (w >> 1) * 32;
    int wn = (w & 1) * 64;
    int srow = (lane >> 2);                          // stage row within 16-row chunk
    int scol = ((lane & 3) ^ ((srow >> 1) & 3)) * 8; // pre-swizzled source col

    f32x4 acc[2][4] = {};

    // prologue: stage k-step 0 into buf 0
    if (w < 4) {   // A: 4 chunks of 1 KB
        int row = w * 16 + srow;
        GLDS16(hm + (size_t)(m0 + row) * 224 + scol, lA[0] + w * 512);
    }
    for (int c = w; c < 8; c += 4) {   // B: 8 chunks
        int row = c * 16 + srow;
        int rowB = n0 + row; if (rowB > 99999) rowB = 99999;
        GLDS16(em + (size_t)rowB * 224 + scol, lB[0] + c * 512);
    }
    __syncthreads();

    for (int step = 0; step < 7; ++step) {
        int cur = step & 1;
        if (step < 6) {
            int kk = (step + 1) * 32;
            int nxt = cur ^ 1;
            if (w < 4) {
                int row = w * 16 + srow;
                GLDS16(hm + (size_t)(m0 + row) * 224 + kk + scol, lA[nxt] + w * 512);
            }
            for (int c = w; c < 8; c += 4) {
                int row = c * 16 + srow;
                int rowB = n0 + row; if (rowB > 99999) rowB = 99999;
                GLDS16(em + (size_t)rowB * 224 + kk + scol, lB[nxt] + c * 512);
            }
        }
        const ushort_t* A = lA[cur];
        const ushort_t* B = lB[cur];
        bf16x8 af[2], bfr[4];
        #pragma unroll
        for (int mf = 0; mf < 2; ++mf) {
            int r = wm + mf * 16 + (lane & 15);
            int pc = ((lane >> 4) ^ ((r >> 1) & 3)) * 8;
            af[mf] = *reinterpret_cast<const bf16x8*>(A + r * 32 + pc);
        }
        #pragma unroll
        for (int nf = 0; nf < 4; ++nf) {
            int r = wn + nf * 16 + (lane & 15);
            int pc = ((lane >> 4) ^ ((r >> 1) & 3)) * 8;
            bfr[nf] = *reinterpret_cast<const bf16x8*>(B + r * 32 + pc);
        }
        // swapped operands: D^T fragment — lane&15 -> M row, (lane>>4)*4+j -> N col
        #pragma unroll
        for (int mf = 0; mf < 2; ++mf)
            #pragma unroll
            for (int nf = 0; nf < 4; ++nf)
                acc[mf][nf] = __builtin_amdgcn_mfma_f32_16x16x32_bf16(bfr[nf], af[mf], acc[mf][nf], 0, 0, 0);
        __syncthreads();
    }

    // ---- epilogue: bias+sigmoid in regs, transpose via tr, full-line PLAIN stores ----
    int ncol_base = n0 + wn + (lane >> 4) * 4;
    f32x4 b4[4];
    #pragma unroll
    for (int nf = 0; nf < 4; ++nf) {
        int colg = ncol_base + nf * 16;
        b4[nf] = (colg < 100000) ? *reinterpret_cast<const f32x4*>(out_bias + colg)
                                 : f32x4{0.f, 0.f, 0.f, 0.f};
    }
    int lr = (w >> 1) * 16 + (lane & 15);            // local row slot 0..31 per half
    int lcw = wn + (lane >> 4) * 4;                  // local col base
    #pragma unroll
    for (int h = 0; h < 2; ++h) {
        if (h) __syncthreads();                      // protect tr before overwrite
        #pragma unroll
        for (int nf = 0; nf < 4; ++nf) {
            f32x4 x = acc[h][nf];
            f32x4 s;
            #pragma unroll
            for (int q = 0; q < 4; ++q)
                s[q] = __builtin_amdgcn_rcpf(1.f + __expf(-(x[q] + b4[nf][q])));
            *reinterpret_cast<f32x4*>(&tr[lr][lcw + nf * 16]) = s;
        }
        __syncthreads();
        // read back row-contiguous and store: half-wave = 512 B contiguous/inst
        #pragma unroll
        for (int p = 0; p < 4; ++p) {
            int sl = (t >> 5) + p * 8;                             // slot 0..31
            int grow = m0 + (sl >> 4) * 32 + h * 16 + (sl & 15);   // global row
            int gcol = n0 + (t & 31) * 4;
            f32x4 v = *reinterpret_cast<const f32x4*>(&tr[sl][(t & 31) * 4]);
            if (gcol < 100000)   // 100000 % 4 == 0 -> all-or-nothing per float4
                *reinterpret_cast<f32x4*>(out + (size_t)grow * 100000 + gcol) = v;
        }
    }
}

extern "C" void kernel_launch(void* const* d_in, const int* in_sizes, int n_in,
                              void* d_out, int out_size, void* d_ws, size_t ws_size,
                              hipStream_t stream)
{
    const int*   eid      = (const int*)d_in[0];
    const int*   rid      = (const int*)d_in[1];
    const float* ent_emb  = (const float*)d_in[2];
    const float* rel_emb  = (const float*)d_in[3];
    const float* filt_w   = (const float*)d_in[4];
    const float* filt1_w  = (const float*)d_in[5];
    const float* fc_w     = (const float*)d_in[6];
    const float* fc_b     = (const float*)d_in[7];
    const float* out_bias = (const float*)d_in[8];
    const float* bn0_s = (const float*)d_in[9];
    const float* bn0_b = (const float*)d_in[10];
    const float* bn0_m = (const float*)d_in[11];
    const float* bn0_v = (const float*)d_in[12];
    const float* bn1_s = (const float*)d_in[13];
    const float* bn1_b = (const float*)d_in[14];
    const float* bn1_m = (const float*)d_in[15];
    const float* bn1_v = (const float*)d_in[16];
    const float* bn2_s = (const float*)d_in[17];
    const float* bn2_b = (const float*)d_in[18];
    const float* bn2_m = (const float*)d_in[19];
    const float* bn2_v = (const float*)d_in[20];
    float* out = (float*)d_out;

    char* ws = (char*)d_ws;
    ushort_t* E_bf = (ushort_t*)(ws + 0);            // 100000*224*2 = 44,800,000
    ushort_t* act  = (ushort_t*)(ws + 44800000);     // 1024*12800*2 = 26,214,400
    ushort_t* fcw  = (ushort_t*)(ws + 71014400);     // 256*12800*2  =  6,553,600
    float*    part = (float*)(ws + 77568000);        // 20*1024*256*4 = 20,971,520
    ushort_t* hmat = (ushort_t*)(ws + 98539520);     // 1024*224*2   =    458,752

    // 1. ALL independent prep: frontend + fcw convert + ent convert (one dispatch)
    hipLaunchKernelGGL(prep_all_kernel, dim3(1024 + 3200 + 21875), dim3(256), 0, stream,
                       fc_w, fcw,
                       eid, rid, ent_emb, rel_emb, filt_w, filt1_w,
                       bn0_s, bn0_b, bn0_m, bn0_v, bn1_s, bn1_b, bn1_m, bn1_v, act, E_bf);
    // 2. fc gemm (pure, 640 blocks)
    hipLaunchKernelGGL(fc_gemm_kernel, dim3(640), dim3(256), 0, stream,
                       act, fcw, part);
    // 3. reduce + bn2 + relu -> h
    hipLaunchKernelGGL(reduce_bn2_kernel, dim3((1024 * 224) / 256), dim3(256), 0, stream,
                       part, fc_b, bn2_s, bn2_b, bn2_m, bn2_v, hmat);
    // 4. big gemm + sigmoid (64x128 tiles, 12512 blocks, transposed epilogue, plain stores)
    hipLaunchKernelGGL(big_gemm_kernel, dim3(12512), dim3(256), 0, stream,
                       hmat, E_bf, out_bias, out);
}

// Round 14
// 184.869 us; speedup vs baseline: 1.3942x; 1.3942x over previous
//
#include <hip/hip_runtime.h>
#include <hip/hip_bf16.h>

#define EPS 1e-5f

typedef __bf16 bf16x8 __attribute__((ext_vector_type(8)));
typedef float f32x4 __attribute__((ext_vector_type(4)));
typedef unsigned short ushort_t;

#define GLDS16(gp, lp) __builtin_amdgcn_global_load_lds( \
    (const __attribute__((address_space(1))) unsigned int*)(gp), \
    (__attribute__((address_space(3))) unsigned int*)(lp), 16, 0, 0)

__device__ __forceinline__ unsigned short f2bf(float f) {
    unsigned int u = __float_as_uint(f);
    u += 0x7fffu + ((u >> 16) & 1u);   // RNE
    return (unsigned short)(u >> 16);
}

// ---------------- generic f32 [R][C] -> bf16 [R2][C2] zero-padded convert (device fn) ---------
__device__ __forceinline__ void convert_pad_body(
    const float* __restrict__ src, ushort_t* __restrict__ dst,
    int R, int C, int R2, int C2, long long start, long long stride)
{
    int cpr = C2 >> 2;
    long long nchunks = (long long)R2 * cpr;
    for (long long idx = start; idx < nchunks; idx += stride) {
        int row = (int)(idx / cpr);
        int col = ((int)(idx - (long long)row * cpr)) << 2;
        float4 v = make_float4(0.f, 0.f, 0.f, 0.f);
        if (row < R && col < C)
            v = *reinterpret_cast<const float4*>(src + (size_t)row * C + col);
        union { unsigned short h[4]; uint2 u; } pk;
        pk.h[0] = f2bf(v.x); pk.h[1] = f2bf(v.y);
        pk.h[2] = f2bf(v.z); pk.h[3] = f2bf(v.w);
        *reinterpret_cast<uint2*>(dst + (size_t)row * C2 + col) = pk.u;
    }
}

// ---------------- kernel 1: ALL independent prep work in one dispatch ----------------
// blocks [0,1024): frontend   [1024,4224): fcw convert   [4224,26099): ent convert
__global__ __launch_bounds__(256) void prep_all_kernel(
    const float* __restrict__ fc_w, ushort_t* __restrict__ fcw,
    const int* __restrict__ eid, const int* __restrict__ rid,
    const float* __restrict__ ent_emb, const float* __restrict__ rel_emb,
    const float* __restrict__ filt_w, const float* __restrict__ filt1_w,
    const float* __restrict__ bn0_s, const float* __restrict__ bn0_b,
    const float* __restrict__ bn0_m, const float* __restrict__ bn0_v,
    const float* __restrict__ bn1_s, const float* __restrict__ bn1_b,
    const float* __restrict__ bn1_m, const float* __restrict__ bn1_v,
    ushort_t* __restrict__ act, ushort_t* __restrict__ E_bf)
{
    __shared__ float img[20][20];
    __shared__ float fA[16][9];
    __shared__ float fB[16][9];
    __shared__ float a1[16], b1[16];

    int t = threadIdx.x;
    if (blockIdx.x >= 4224) {
        long long start = (long long)(blockIdx.x - 4224) * 256 + t;
        convert_pad_body(ent_emb, E_bf, 100000, 200, 100000, 224, start, 21875LL * 256);
        return;
    }
    if (blockIdx.x >= 1024) {
        long long start = (long long)(blockIdx.x - 1024) * 256 + t;
        convert_pad_body(fc_w, fcw, 200, 12800, 256, 12800, start, 3200LL * 256);
        return;
    }

    int b = blockIdx.x;
    int e = eid[b], r = rid[b];

    float a0 = bn0_s[0] * rsqrtf(bn0_v[0] + EPS);
    float c0 = bn0_b[0] - bn0_m[0] * a0;

    for (int p = t; p < 400; p += 256) {
        int i = p / 20, j = p - (p / 20) * 20;
        int src;
        if (i < 10) src = (j < 10) ? (i * 40 + j) : ((j - 10) * 40 + 30 + i);
        else        src = (j < 10) ? ((i - 10) * 40 + 20 + j) : ((j - 10) * 40 + 10 + (i - 10));
        float v = (src < 200) ? ent_emb[(size_t)e * 200 + src]
                              : rel_emb[(size_t)r * 200 + (src - 200)];
        img[i][j] = v * a0 + c0;
    }
    for (int p = t; p < 144; p += 256) fA[p / 9][p % 9] = filt_w[(size_t)r * 144 + p];
    for (int p = t; p < 144; p += 256) fB[p / 9][p % 9] = filt1_w[(size_t)r * 144 + p];
    if (t < 16) {
        float a = bn1_s[t] * rsqrtf(bn1_v[t] + EPS);
        a1[t] = a;
        b1[t] = bn1_b[t] - bn1_m[t] * a;
    }
    __syncthreads();

    for (int idx = t; idx < 12800; idx += 256) {
        int c = idx / 400;
        int p = idx - c * 400;
        int i = p / 20, j = p - (p / 20) * 20;
        int ch = c & 15;
        float acc = 0.f;
        if (c < 16) {
            #pragma unroll
            for (int di = 0; di < 3; ++di) {
                int ii = i + di - 1;
                if (ii < 0 || ii >= 20) continue;
                #pragma unroll
                for (int dj = 0; dj < 3; ++dj) {
                    int jj = j + dj - 1;
                    if (jj >= 0 && jj < 20) acc += img[ii][jj] * fA[ch][di * 3 + dj];
                }
            }
        } else {
            #pragma unroll
            for (int dj = 0; dj < 9; ++dj) {
                int jj = j + dj - 4;
                if (jj >= 0 && jj < 20) acc += img[i][jj] * fB[ch][dj];
            }
        }
        float v = fmaxf(acc * a1[ch] + b1[ch], 0.f);
        act[(size_t)b * 12800 + idx] = f2bf(v);
    }
}

// ---------------- kernel 2: fc GEMM only (640 blocks, split-K=20) ----------------
__global__ __launch_bounds__(256) void fc_gemm_kernel(
    const ushort_t* __restrict__ act,   // [1024][12800] bf16
    const ushort_t* __restrict__ fcw,   // [256][12800] bf16 (rows 200.. zero)
    float* __restrict__ part)           // [20][1024][256] f32
{
    __shared__ ushort_t lA[128 * 64];
    __shared__ ushort_t lB[64 * 64];

    int t = threadIdx.x;
    int bx = blockIdx.x;
    int mt = bx & 7;
    int nt = (bx >> 3) & 3;
    int ks = bx >> 5;
    int m0 = mt * 128, n0 = nt * 64, k0 = ks * 640;

    int lane = t & 63, w = t >> 6;
    int wm = (w >> 1) * 64;
    int wn = (w & 1) * 32;

    f32x4 acc[4][2] = {};

    for (int step = 0; step < 10; ++step) {
        int kk = k0 + step * 64;
        for (int c = w; c < 16; c += 4) {
            int elem = c * 512 + lane * 8;
            int row = elem >> 6, col = elem & 63;
            GLDS16(act + (size_t)(m0 + row) * 12800 + kk + col, lA + c * 512);
        }
        for (int c = w; c < 8; c += 4) {
            int elem = c * 512 + lane * 8;
            int row = elem >> 6, col = elem & 63;
            GLDS16(fcw + (size_t)(n0 + row) * 12800 + kk + col, lB + c * 512);
        }
        __syncthreads();
        #pragma unroll
        for (int kq = 0; kq < 2; ++kq) {
            bf16x8 af[4], bfr[2];
            #pragma unroll
            for (int mf = 0; mf < 4; ++mf) {
                int row = wm + mf * 16 + (lane & 15);
                af[mf] = *reinterpret_cast<const bf16x8*>(lA + row * 64 + kq * 32 + (lane >> 4) * 8);
            }
            #pragma unroll
            for (int nf = 0; nf < 2; ++nf) {
                int row = wn + nf * 16 + (lane & 15);
                bfr[nf] = *reinterpret_cast<const bf16x8*>(lB + row * 64 + kq * 32 + (lane >> 4) * 8);
            }
            #pragma unroll
            for (int mf = 0; mf < 4; ++mf)
                #pragma unroll
                for (int nf = 0; nf < 2; ++nf)
                    acc[mf][nf] = __builtin_amdgcn_mfma_f32_16x16x32_bf16(af[mf], bfr[nf], acc[mf][nf], 0, 0, 0);
        }
        __syncthreads();
    }

    float* outp = part + (size_t)ks * 1024 * 256;
    #pragma unroll
    for (int mf = 0; mf < 4; ++mf) {
        #pragma unroll
        for (int nf = 0; nf < 2; ++nf) {
            int colg = n0 + wn + nf * 16 + (lane & 15);
            int rowb = (lane >> 4) * 4;
            #pragma unroll
            for (int j = 0; j < 4; ++j) {
                int rowg = m0 + wm + mf * 16 + rowb + j;
                outp[(size_t)rowg * 256 + colg] = acc[mf][nf][j];
            }
        }
    }
}

// ---------------- reduce partials + fc_b + bn2 + relu -> h bf16 [1024][224] ----------------
__global__ __launch_bounds__(256) void reduce_bn2_kernel(
    const float* __restrict__ part, const float* __restrict__ fc_b,
    const float* __restrict__ bn2_s, const float* __restrict__ bn2_b,
    const float* __restrict__ bn2_m, const float* __restrict__ bn2_v,
    ushort_t* __restrict__ h)
{
    int idx = blockIdx.x * 256 + threadIdx.x;
    if (idx >= 1024 * 224) return;
    int m = idx / 224, n = idx - m * 224;
    float v = 0.f;
    if (n < 200) {
        float s = 0.f;
        #pragma unroll 4
        for (int k = 0; k < 20; ++k) s += part[(size_t)k * 1024 * 256 + (size_t)m * 256 + n];
        s += fc_b[n];
        float a = bn2_s[n] * rsqrtf(bn2_v[n] + EPS);
        v = fmaxf((s - bn2_m[n]) * a + bn2_b[n], 0.f);
    }
    h[idx] = f2bf(v);
}

// ---------------- big GEMM v13: R12 + QUARTER transpose buffer -> 4 blocks/CU ----------------
// h[1024][224] x E[100000][224]^T + bias -> sigmoid -> out [1024][100000]
// Single change vs the R12 champion (NT + transposed epilogue): tr shrinks
// [32][132] (16.9 KB) -> [32][68] (8.5 KB, one 64-col half per pass). LDS
// 41.5 -> 32.7 KB => 3 -> 4 blocks/CU. Per-inst contiguity 512 -> 256 B —
// still full aligned 128-B lines, preserving the proven line-coverage win.
__global__ __launch_bounds__(256) void big_gemm_kernel(
    const ushort_t* __restrict__ hm,    // [1024][224] bf16
    const ushort_t* __restrict__ em,    // [100000][224] bf16 (cols 200.. zero)
    const float* __restrict__ out_bias, // [100000]
    float* __restrict__ out)            // [1024][100000]
{
    __shared__ ushort_t lA[2][64 * 32];    // 4 KB x2
    __shared__ ushort_t lB[2][128 * 32];   // 8 KB x2
    __shared__ float tr[32][68];           // 8.5 KB transpose region (half N-tile)

    // bijective XCD swizzle: 12512 = 8 x 1564
    int phys = blockIdx.x;
    int virt = (phys & 7) * 1564 + (phys >> 3);
    int mt = virt & 15;     // 16 M tiles of 64 rows
    int nt = virt >> 4;     // 782 N tiles of 128 cols
    int m0 = mt * 64, n0 = nt * 128;

    int t = threadIdx.x;
    int lane = t & 63, w = t >> 6;
    int wm = (w >> 1) * 32;
    int wn = (w & 1) * 64;
    int srow = (lane >> 2);                          // stage row within 16-row chunk
    int scol = ((lane & 3) ^ ((srow >> 1) & 3)) * 8; // pre-swizzled source col

    f32x4 acc[2][4] = {};

    // prologue: stage k-step 0 into buf 0
    if (w < 4) {   // A: 4 chunks of 1 KB
        int row = w * 16 + srow;
        GLDS16(hm + (size_t)(m0 + row) * 224 + scol, lA[0] + w * 512);
    }
    for (int c = w; c < 8; c += 4) {   // B: 8 chunks
        int row = c * 16 + srow;
        int rowB = n0 + row; if (rowB > 99999) rowB = 99999;
        GLDS16(em + (size_t)rowB * 224 + scol, lB[0] + c * 512);
    }
    __syncthreads();

    for (int step = 0; step < 7; ++step) {
        int cur = step & 1;
        if (step < 6) {
            int kk = (step + 1) * 32;
            int nxt = cur ^ 1;
            if (w < 4) {
                int row = w * 16 + srow;
                GLDS16(hm + (size_t)(m0 + row) * 224 + kk + scol, lA[nxt] + w * 512);
            }
            for (int c = w; c < 8; c += 4) {
                int row = c * 16 + srow;
                int rowB = n0 + row; if (rowB > 99999) rowB = 99999;
                GLDS16(em + (size_t)rowB * 224 + kk + scol, lB[nxt] + c * 512);
            }
        }
        const ushort_t* A = lA[cur];
        const ushort_t* B = lB[cur];
        bf16x8 af[2], bfr[4];
        #pragma unroll
        for (int mf = 0; mf < 2; ++mf) {
            int r = wm + mf * 16 + (lane & 15);
            int pc = ((lane >> 4) ^ ((r >> 1) & 3)) * 8;
            af[mf] = *reinterpret_cast<const bf16x8*>(A + r * 32 + pc);
        }
        #pragma unroll
        for (int nf = 0; nf < 4; ++nf) {
            int r = wn + nf * 16 + (lane & 15);
            int pc = ((lane >> 4) ^ ((r >> 1) & 3)) * 8;
            bfr[nf] = *reinterpret_cast<const bf16x8*>(B + r * 32 + pc);
        }
        // swapped operands: D^T fragment — lane&15 -> M row, (lane>>4)*4+j -> N col
        #pragma unroll
        for (int mf = 0; mf < 2; ++mf)
            #pragma unroll
            for (int nf = 0; nf < 4; ++nf)
                acc[mf][nf] = __builtin_amdgcn_mfma_f32_16x16x32_bf16(bfr[nf], af[mf], acc[mf][nf], 0, 0, 0);
        __syncthreads();
    }

    // ---- epilogue: 4 passes (mf-half h x col-half c), transpose via tr[32][68],
    //      full-line NT stores (256 B contiguous per 16 lanes) ----
    int ncol_base = n0 + wn + (lane >> 4) * 4;
    f32x4 b4[4];
    #pragma unroll
    for (int nf = 0; nf < 4; ++nf) {
        int colg = ncol_base + nf * 16;
        b4[nf] = (colg < 100000) ? *reinterpret_cast<const f32x4*>(out_bias + colg)
                                 : f32x4{0.f, 0.f, 0.f, 0.f};
    }
    int lr = (w >> 1) * 16 + (lane & 15);            // local row slot 0..31
    int lc4 = (lane >> 4) * 4;                       // col quad within 64-col half
    bool first = true;
    #pragma unroll
    for (int h = 0; h < 2; ++h) {
        #pragma unroll
        for (int c = 0; c < 2; ++c) {
            if (!first) __syncthreads();             // protect tr before overwrite
            first = false;
            if ((w & 1) == c) {
                // writers: threads whose wn-half == c; their 4 frags = cols 0..63 of half
                #pragma unroll
                for (int nf = 0; nf < 4; ++nf) {
                    f32x4 x = acc[h][nf];
                    f32x4 s;
                    #pragma unroll
                    for (int q = 0; q < 4; ++q)
                        s[q] = __builtin_amdgcn_rcpf(1.f + __expf(-(x[q] + b4[nf][q])));
                    *reinterpret_cast<f32x4*>(&tr[lr][lc4 + nf * 16]) = s;
                }
            }
            __syncthreads();
            // readback: all 256 threads; 16 B/thread, 16 lanes = 256 B contiguous/row
            #pragma unroll
            for (int p = 0; p < 2; ++p) {
                int sl = (t >> 4) + p * 16;                            // slot 0..31
                int grow = m0 + (sl >> 4) * 32 + h * 16 + (sl & 15);   // global row
                int gcol = n0 + c * 64 + (t & 15) * 4;
                f32x4 v = *reinterpret_cast<const f32x4*>(&tr[sl][(t & 15) * 4]);
                if (gcol < 100000)   // 100000 % 4 == 0 -> all-or-nothing per float4
                    __builtin_nontemporal_store(v, reinterpret_cast<f32x4*>(out + (size_t)grow * 100000 + gcol));
            }
        }
    }
}

extern "C" void kernel_launch(void* const* d_in, const int* in_sizes, int n_in,
                              void* d_out, int out_size, void* d_ws, size_t ws_size,
                              hipStream_t stream)
{
    const int*   eid      = (const int*)d_in[0];
    const int*   rid      = (const int*)d_in[1];
    const float* ent_emb  = (const float*)d_in[2];
    const float* rel_emb  = (const float*)d_in[3];
    const float* filt_w   = (const float*)d_in[4];
    const float* filt1_w  = (const float*)d_in[5];
    const float* fc_w     = (const float*)d_in[6];
    const float* fc_b     = (const float*)d_in[7];
    const float* out_bias = (const float*)d_in[8];
    const float* bn0_s = (const float*)d_in[9];
    const float* bn0_b = (const float*)d_in[10];
    const float* bn0_m = (const float*)d_in[11];
    const float* bn0_v = (const float*)d_in[12];
    const float* bn1_s = (const float*)d_in[13];
    const float* bn1_b = (const float*)d_in[14];
    const float* bn1_m = (const float*)d_in[15];
    const float* bn1_v = (const float*)d_in[16];
    const float* bn2_s = (const float*)d_in[17];
    const float* bn2_b = (const float*)d_in[18];
    const float* bn2_m = (const float*)d_in[19];
    const float* bn2_v = (const float*)d_in[20];
    float* out = (float*)d_out;

    char* ws = (char*)d_ws;
    ushort_t* E_bf = (ushort_t*)(ws + 0);            // 100000*224*2 = 44,800,000
    ushort_t* act  = (ushort_t*)(ws + 44800000);     // 1024*12800*2 = 26,214,400
    ushort_t* fcw  = (ushort_t*)(ws + 71014400);     // 256*12800*2  =  6,553,600
    float*    part = (float*)(ws + 77568000);        // 20*1024*256*4 = 20,971,520
    ushort_t* hmat = (ushort_t*)(ws + 98539520);     // 1024*224*2   =    458,752

    // 1. ALL independent prep: frontend + fcw convert + ent convert (one dispatch)
    hipLaunchKernelGGL(prep_all_kernel, dim3(1024 + 3200 + 21875), dim3(256), 0, stream,
                       fc_w, fcw,
                       eid, rid, ent_emb, rel_emb, filt_w, filt1_w,
                       bn0_s, bn0_b, bn0_m, bn0_v, bn1_s, bn1_b, bn1_m, bn1_v, act, E_bf);
    // 2. fc gemm (pure, 640 blocks)
    hipLaunchKernelGGL(fc_gemm_kernel, dim3(640), dim3(256), 0, stream,
                       act, fcw, part);
    // 3. reduce + bn2 + relu -> h
    hipLaunchKernelGGL(reduce_bn2_kernel, dim3((1024 * 224) / 256), dim3(256), 0, stream,
                       part, fc_b, bn2_s, bn2_b, bn2_m, bn2_v, hmat);
    // 4. big gemm + sigmoid (64x128 tiles, 12512 blocks, quarter-transpose NT epilogue)
    hipLaunchKernelGGL(big_gemm_kernel, dim3(12512), dim3(256), 0, stream,
                       hmat, E_bf, out_bias, out);
}